// Round 2
// baseline (2233.141 us; speedup 1.0000x reference)
//
#include <hip/hip_runtime.h>
#include <hip/hip_bf16.h>

// Problem constants
#define B_  64
#define T_  512
#define E_  256
#define H_  512
#define G4_ 2048
#define C_  4

typedef __attribute__((ext_vector_type(4))) float  f32x4;
typedef __attribute__((ext_vector_type(8))) __bf16 bf16x8;
typedef __attribute__((ext_vector_type(8))) short  short8;   // no HIP builtin 'short8'
typedef __attribute__((ext_vector_type(4))) short  s16x4;    // HIP predefines 'short4'

union V16 { f32x4 f; bf16x8 b; short8 s; };

__device__ __forceinline__ float sigmoid_(float x) { return 1.0f / (1.0f + __expf(-x)); }
__device__ __forceinline__ float tanh_(float x)    { return 1.0f - 2.0f / (__expf(2.0f * x) + 1.0f); }

// Deterministic RNE fp32 -> bf16
__device__ __forceinline__ short f2bf(float f) {
  union { float f; unsigned u; } v; v.f = f;
  return (short)((v.u + 0x7FFFu + ((v.u >> 16) & 1u)) >> 16);
}

// --- per-access MALL-coherent ops (sc0 sc1 = bypass L1+L2, coherent point) ---
__device__ __forceinline__ void store_dword_llc_f(void* p, float v) {
  asm volatile("global_store_dword %0, %1, off sc0 sc1" :: "v"(p), "v"(v) : "memory");
}
__device__ __forceinline__ void store_dword_llc_u(void* p, unsigned v) {
  asm volatile("global_store_dword %0, %1, off sc0 sc1" :: "v"(p), "v"(v) : "memory");
}
// two coherent 16B loads, one drain (poll quantum = 32 B)
// NOTE gfx950 assembler: offset: must precede sc0 sc1.
__device__ __forceinline__ void ld2_b128_llc(const void* p, f32x4& a, f32x4& b) {
  asm volatile("global_load_dwordx4 %0, %2, off sc0 sc1\n\t"
               "global_load_dwordx4 %1, %2, off offset:16 sc0 sc1\n\t"
               "s_waitcnt vmcnt(0)"
               : "=&v"(a), "=&v"(b) : "v"(p) : "memory");
}

// ---------------------------------------------------------------------------
// One-time W_ih fp32 -> bf16 converter (r9 win).
// ---------------------------------------------------------------------------
__global__ __launch_bounds__(256, 1) void wih_conv(const float* __restrict__ W,
                                                   short* __restrict__ out) {
  const int i = (blockIdx.x * 256 + threadIdx.x) * 4;   // grid 512 -> 524288 elems
  f32x4 v = *(const f32x4*)(W + i);
  s16x4 s;
  s[0] = f2bf(v[0]); s[1] = f2bf(v[1]); s[2] = f2bf(v[2]); s[3] = f2bf(v[3]);
  *(s16x4*)(out + i) = s;
}

// ---------------------------------------------------------------------------
// Phase 1: xg[t][g][b][d] = (emb[x[b][t]] @ W_ih^T)[g*512+d]  (bias added later)
// Unchanged from the 1263 us kernel (r14 coalesced C-write version).
// ---------------------------------------------------------------------------
union XgSmem {
  struct { int idx[B_]; short e[B_][E_ + 8]; } g;   // gather phase (34 KB)
  short o[4][64][136];                              // epilogue staging (68 KB)
};

template<bool WBF16>
__global__ __launch_bounds__(256, 2) void xg_kernel(
    const int* __restrict__ x, const float* __restrict__ emb,
    const void* __restrict__ Wv,
    __hip_bfloat16* __restrict__ xg)
{
  const int t   = blockIdx.x;
  const int tid = threadIdx.x;
  __shared__ XgSmem sm;

  if (tid < B_) sm.g.idx[tid] = x[tid * T_ + t];
  __syncthreads();
  {
    int b = tid >> 2, ch = tid & 3;
    const float* src = emb + (size_t)sm.g.idx[b] * E_ + ch * 64;
    short* dst = &sm.g.e[b][ch * 64];
#pragma unroll
    for (int i = 0; i < 16; i++) {
      f32x4 v = *(const f32x4*)(src + i * 4);
      s16x4 s;
      s[0] = f2bf(v[0]); s[1] = f2bf(v[1]); s[2] = f2bf(v[2]); s[3] = f2bf(v[3]);
      *(s16x4*)(dst + i * 4) = s;
    }
  }
  __syncthreads();

  const int wv   = tid >> 6;
  const int lane = tid & 63;
  const int ln15 = lane & 15, quad = lane >> 4;

  // B operand fully captured in registers; s_e is dead after this.
  V16 breg[4][8];
#pragma unroll
  for (int nt = 0; nt < 4; nt++)
#pragma unroll
    for (int ks = 0; ks < 8; ks++)
      breg[nt][ks].f = *(const f32x4*)(&sm.g.e[nt * 16 + ln15][quad * 8 + ks * 32]);
  __syncthreads();   // all waves done reading s_e before s_o overwrites it

  const int gbase = wv * 512;
  const size_t base_t = (size_t)t * (G4_ * B_);

  for (int q = 0; q < 4; q++) {          // quarter = 8 M-tiles = dims [q*128,+128)
#pragma unroll
    for (int m8 = 0; m8 < 8; m8++) {
      const int mt = q * 8 + m8;
      V16 areg[8];
      if constexpr (WBF16) {
        const short* arow = (const short*)Wv + (size_t)(gbase + mt * 16 + ln15) * E_ + quad * 8;
#pragma unroll
        for (int ks = 0; ks < 8; ks++)
          areg[ks].f = *(const f32x4*)(arow + ks * 32);
      } else {
        const float* arow = (const float*)Wv + (size_t)(gbase + mt * 16 + ln15) * E_ + quad * 8;
#pragma unroll
        for (int ks = 0; ks < 8; ks++) {
          f32x4 lo = *(const f32x4*)(arow + ks * 32);
          f32x4 hi = *(const f32x4*)(arow + ks * 32 + 4);
          short8 s;
          s[0] = f2bf(lo[0]); s[1] = f2bf(lo[1]); s[2] = f2bf(lo[2]); s[3] = f2bf(lo[3]);
          s[4] = f2bf(hi[0]); s[5] = f2bf(hi[1]); s[6] = f2bf(hi[2]); s[7] = f2bf(hi[3]);
          areg[ks].s = s;
        }
      }

      f32x4 acc[4];
#pragma unroll
      for (int nt = 0; nt < 4; nt++) acc[nt] = (f32x4){0.f, 0.f, 0.f, 0.f};
#pragma unroll
      for (int ks = 0; ks < 8; ks++)
#pragma unroll
        for (int nt = 0; nt < 4; nt++)
          acc[nt] = __builtin_amdgcn_mfma_f32_16x16x32_bf16(areg[ks].b, breg[nt][ks].b, acc[nt], 0, 0, 0);

      // stage C tile into wave-private LDS (2-way bank aliasing only)
      const int dl = m8 * 16 + quad * 4;
#pragma unroll
      for (int nt = 0; nt < 4; nt++) {
        const int batch = nt * 16 + ln15;
        s16x4 sv;
#pragma unroll
        for (int r = 0; r < 4; r++) sv[r] = f2bf(acc[nt][r]);
        *(s16x4*)&sm.o[wv][batch][dl] = sv;
      }
    }

    // drain quarter: 16 b128 insts; lanes 0-15 = one batch row's 256 B
    const size_t qbase = base_t + ((size_t)wv << 15) + q * 128;
    const int chunk = lane & 15;
#pragma unroll
    for (int i = 0; i < 16; i++) {
      const int row = (lane >> 4) + i * 4;
      f32x4 v = *(const f32x4*)&sm.o[wv][row][chunk * 8];
      *(f32x4*)((short*)xg + qbase + ((size_t)row << 9) + chunk * 8) = v;
    }
  }
}

// ---------------------------------------------------------------------------
// Phase 2: persistent recurrent kernel — EPOCH-FUSED h exchange.
// r15: each h word carried as dword (epoch<<16)|bf16(h); consumers poll the
// data itself. Removes the flag RT + producer drain RT (3 MALL RTs -> ~1) and
// the per-step flag spin. Gate math moved fully into registers: wave wv owns
// all 4 gates of dims [d0+wv*8,+8), A-tile row = dim_local*4 + gate, so each
// lane's acc[r] = preact of gate r for one (batch,dim) -> no s_pre LDS, no S3.
// s_h double-buffered -> ONE __syncthreads per step (was 4).
// Depth-2 slot reuse safe without fences: writing epoch t+2 into slot t&1
// requires h_{t+1} consumed, which requires every consumer staged h_t.
// ---------------------------------------------------------------------------
__global__ __launch_bounds__(512, 2) void lstm_kernel(
    const float* __restrict__ W_hh,
    const float* __restrict__ b_ih, const float* __restrict__ b_hh,
    const float* __restrict__ W_fc, const float* __restrict__ b_fc,
    const __hip_bfloat16* __restrict__ xg,
    unsigned int* flags, unsigned int* hbuf /*[2][64][512] dwords*/, float* hT,
    float* out)
{
  const int tid  = threadIdx.x;
  const int blk  = blockIdx.x;
  const int g    = blk & 7;        // batch group (8 batches)
  const int pd   = blk >> 3;       // dim slice [pd*64, +64)
  const int d0   = pd * 64;
  const int wv   = tid >> 6;       // 0..7
  const int lane = tid & 63;
  const int ln15 = lane & 15, quad = lane >> 4;

  __shared__ __hip_bfloat16 s_h[2][16][520];   // double-buffered; rows 8-15 zero

  // A-regs: wave wv owns dims [d0+wv*8, +8), ALL 4 gates.
  // Tile tau covers dims d0+wv*8+tau*4..+4; A row m: gate=m&3, dim_local=m>>2.
  // D layout (col=lane&15=batch, row=quad*4+r): acc[tau][r] = gate r preact of
  // dim d0+wv*8+tau*4+quad, batch ln15. K-order identical to r10 -> bitwise.
  V16 areg[2][16];
#pragma unroll
  for (int tau = 0; tau < 2; tau++) {
    const int grow = (ln15 & 3) * 512 + d0 + wv * 8 + tau * 4 + (ln15 >> 2);
    const float* ap = W_hh + (size_t)grow * H_ + quad * 8;
#pragma unroll
    for (int ks = 0; ks < 16; ks++) {
      f32x4 lo = *(const f32x4*)(ap + ks * 32);
      f32x4 hi = *(const f32x4*)(ap + ks * 32 + 4);
      short8 s;
      s[0] = f2bf(lo[0]); s[1] = f2bf(lo[1]); s[2] = f2bf(lo[2]); s[3] = f2bf(lo[3]);
      s[4] = f2bf(hi[0]); s[5] = f2bf(hi[1]); s[6] = f2bf(hi[2]); s[7] = f2bf(hi[3]);
      areg[tau][ks].s = s;
    }
  }

  // per-lane LSTM state (valid lanes: ln15 < 8)
  const int gb_ = g * 8 + ln15;               // global batch
  float bias[2][4];
  float cst[2] = {0.f, 0.f};
  __hip_bfloat16 xv[2][4];
  if (ln15 < 8) {
#pragma unroll
    for (int tau = 0; tau < 2; tau++) {
      const int dg_ = d0 + wv * 8 + tau * 4 + quad;
#pragma unroll
      for (int gg = 0; gg < 4; gg++)
        bias[tau][gg] = b_ih[gg * 512 + dg_] + b_hh[gg * 512 + dg_];
    }
    // prefetch xg for t=0
    const size_t xb = ((size_t)gb_ << 9);
#pragma unroll
    for (int tau = 0; tau < 2; tau++) {
      const int dg_ = d0 + wv * 8 + tau * 4 + quad;
#pragma unroll
      for (int gg = 0; gg < 4; gg++)
        xv[tau][gg] = xg[xb + ((size_t)gg << 15) + dg_];
    }
  }

  // zero the phantom batch rows of both LDS buffers (MFMA B rows 8-15)
  *(f32x4*)&s_h[0][8 + wv][lane * 8] = (f32x4){0.f, 0.f, 0.f, 0.f};
  *(f32x4*)&s_h[1][8 + wv][lane * 8] = (f32x4){0.f, 0.f, 0.f, 0.f};

  // poll/stage addresses: thread covers batch tid>>6, dims (tid&63)*8 .. +8
  const unsigned* hb0 = hbuf + ((size_t)(g * 8) << 9) + tid * 8;
  const unsigned* hb1 = hb0 + B_ * H_;
  unsigned* sb0 = hbuf + ((size_t)gb_ << 9);       // store base, slot 0
  unsigned* sb1 = sb0 + B_ * H_;                   // store base, slot 1

  for (int t = 0; t < T_; t++) {
    // ---- poll h(t): every dword self-validates via its epoch (high 16) ----
    {
      const unsigned want = (unsigned)t;
      const unsigned* hb = (t & 1) ? hb1 : hb0;
      f32x4 va, vb;
      for (;;) {
        ld2_b128_llc(hb, va, vb);
        unsigned bad = 0;
#pragma unroll
        for (int i = 0; i < 4; i++) {
          bad |= (__float_as_uint(va[i]) >> 16) ^ want;
          bad |= (__float_as_uint(vb[i]) >> 16) ^ want;
        }
        if (!bad) break;
      }
      short8 sv;
      sv[0] = (short)(__float_as_uint(va[0]) & 0xffffu);
      sv[1] = (short)(__float_as_uint(va[1]) & 0xffffu);
      sv[2] = (short)(__float_as_uint(va[2]) & 0xffffu);
      sv[3] = (short)(__float_as_uint(va[3]) & 0xffffu);
      sv[4] = (short)(__float_as_uint(vb[0]) & 0xffffu);
      sv[5] = (short)(__float_as_uint(vb[1]) & 0xffffu);
      sv[6] = (short)(__float_as_uint(vb[2]) & 0xffffu);
      sv[7] = (short)(__float_as_uint(vb[3]) & 0xffffu);
      *(short8*)&s_h[t & 1][tid >> 6][(tid & 63) * 8] = sv;
    }
    __syncthreads();   // the ONLY barrier per step (dbuf s_h protects the rest)

    f32x4 acc0 = (f32x4){0.f, 0.f, 0.f, 0.f};
    f32x4 acc1 = (f32x4){0.f, 0.f, 0.f, 0.f};
#pragma unroll
    for (int ks = 0; ks < 16; ks++) {
      V16 b0;
      b0.f = *(const f32x4*)&s_h[t & 1][ln15][quad * 8 + ks * 32];
      acc0 = __builtin_amdgcn_mfma_f32_16x16x32_bf16(areg[0][ks].b, b0.b, acc0, 0, 0, 0);
      acc1 = __builtin_amdgcn_mfma_f32_16x16x32_bf16(areg[1][ks].b, b0.b, acc1, 0, 0, 0);
    }

    if (ln15 < 8) {
      unsigned* sb = (t & 1) ? sb0 : sb1;        // slot (t+1)&1
#pragma unroll
      for (int tau = 0; tau < 2; tau++) {
        const f32x4 a = tau ? acc1 : acc0;
        const float pi = a[0] + bias[tau][0] + __bfloat162float(xv[tau][0]);
        const float pf = a[1] + bias[tau][1] + __bfloat162float(xv[tau][1]);
        const float pg = a[2] + bias[tau][2] + __bfloat162float(xv[tau][2]);
        const float po = a[3] + bias[tau][3] + __bfloat162float(xv[tau][3]);
        const float i_ = sigmoid_(pi), f_ = sigmoid_(pf);
        const float g_ = tanh_(pg),    o_ = sigmoid_(po);
        cst[tau] = f_ * cst[tau] + i_ * g_;
        const float h = o_ * tanh_(cst[tau]);
        const int dg_ = d0 + wv * 8 + tau * 4 + quad;
        if (t < T_ - 1) {
          const unsigned pw = ((unsigned)(t + 1) << 16) | (unsigned)(unsigned short)f2bf(h);
          store_dword_llc_u(sb + dg_, pw);       // fire-and-forget; data IS the flag
        } else {
          store_dword_llc_f(hT + gb_ * H_ + dg_, h);
        }
      }
      // prefetch xg(t+1): retired for free by next poll's vmcnt(0)
      if (t + 1 < T_) {
        const size_t xb = (size_t)(t + 1) * (G4_ * B_) + ((size_t)gb_ << 9);
#pragma unroll
        for (int tau = 0; tau < 2; tau++) {
          const int dg_ = d0 + wv * 8 + tau * 4 + quad;
#pragma unroll
          for (int gg = 0; gg < 4; gg++)
            xv[tau][gg] = xg[xb + ((size_t)gg << 15) + dg_];
        }
      }
    }
  }

  // one-time completion handoff for the FC epilogue
  asm volatile("s_waitcnt vmcnt(0)" ::: "memory");
  __syncthreads();
  if (tid == 0)
    __hip_atomic_store(&flags[g * 16 + pd], 1u,
                       __ATOMIC_RELAXED, __HIP_MEMORY_SCOPE_AGENT);

  // Phase 3: fp32 FC by block 0
  if (blk == 0) {
    if (tid < 64)
      while (__hip_atomic_load(flags + (tid >> 3) * 16 + (tid & 7),
                               __ATOMIC_RELAXED, __HIP_MEMORY_SCOPE_AGENT) < 1u) {}
    __builtin_amdgcn_fence(__ATOMIC_ACQUIRE, "agent");
    __syncthreads();
    for (int o = tid; o < B_ * C_; o += 512) {
      const int b = o >> 2, cl = o & 3;
      const f32x4* hr = (const f32x4*)(hT + b * H_);
      const f32x4* wr = (const f32x4*)(W_fc + cl * H_);
      float s = 0.f;
      for (int d4 = 0; d4 < H_ / 4; d4++) {
        const f32x4 hv = hr[d4];
        const f32x4 wv4 = wr[d4];
        s += hv[0] * wv4[0] + hv[1] * wv4[1] + hv[2] * wv4[2] + hv[3] * wv4[3];
      }
      s += b_fc[cl];
      out[o] = s;
    }
  }
}

// ---------------------------------------------------------------------------
// Workspace map:
//   [0, 1024)            : flags[256] (block (g,pd) -> word g*16+pd; end-only)
//   [4096, 266240)       : hbuf[2][64][512] dwords: (epoch<<16)|bf16(h)
//                          (memset 0 == epoch 0 + h0 == 0: t=0 passes free)
//   [266240, 397312)     : hT[64][512] fp32
//   [524288, 134742016)  : xg[T][4][B][512] bf16 (128 MiB)
//   [134742016, 135790592): W_ih bf16 table (1 MiB) — only if ws_size allows
// ---------------------------------------------------------------------------
extern "C" void kernel_launch(void* const* d_in, const int* in_sizes, int n_in,
                              void* d_out, int out_size, void* d_ws, size_t ws_size,
                              hipStream_t stream) {
  const int*   x    = (const int*)d_in[0];
  const float* emb  = (const float*)d_in[1];
  const float* W_ih = (const float*)d_in[2];
  const float* W_hh = (const float*)d_in[3];
  const float* b_ih = (const float*)d_in[4];
  const float* b_hh = (const float*)d_in[5];
  const float* W_fc = (const float*)d_in[6];
  const float* b_fc = (const float*)d_in[7];
  float* out = (float*)d_out;

  char* ws = (char*)d_ws;
  const size_t XG_OFF  = 524288;
  const size_t XG_END  = XG_OFF + (size_t)T_ * G4_ * B_ * 2;   // 134,742,016
  const size_t NEEDED2 = XG_END + (size_t)G4_ * E_ * 2;        // +1 MiB bf16 W_ih
  if (ws_size < XG_END) return;

  unsigned int*   flags = (unsigned int*)ws;
  unsigned int*   hbuf  = (unsigned int*)(ws + 4096);
  float*          hT    = (float*)(ws + 266240);
  __hip_bfloat16* xg    = (__hip_bfloat16*)(ws + XG_OFF);
  short*          wih16 = (short*)(ws + XG_END);

  (void)hipMemsetAsync(ws, 0, 266240, stream);

  if (ws_size >= NEEDED2) {
    wih_conv<<<512, 256, 0, stream>>>(W_ih, wih16);
    xg_kernel<true><<<T_, 256, 0, stream>>>(x, emb, wih16, xg);
  } else {
    xg_kernel<false><<<T_, 256, 0, stream>>>(x, emb, W_ih, xg);
  }
  lstm_kernel<<<64, 512, 0, stream>>>(W_hh, b_ih, b_hh, W_fc, b_fc, xg,
                                      flags, hbuf, hT, out);
}

// Round 4
// 1656.857 us; speedup vs baseline: 1.3478x; 1.3478x over previous
//
#include <hip/hip_runtime.h>
#include <hip/hip_bf16.h>

// Problem constants
#define B_  64
#define T_  512
#define E_  256
#define H_  512
#define G4_ 2048
#define C_  4

typedef __attribute__((ext_vector_type(4))) float  f32x4;
typedef __attribute__((ext_vector_type(8))) __bf16 bf16x8;
typedef __attribute__((ext_vector_type(8))) short  short8;   // no HIP builtin 'short8'
typedef __attribute__((ext_vector_type(4))) short  s16x4;    // HIP predefines 'short4'

union V16 { f32x4 f; bf16x8 b; short8 s; };

__device__ __forceinline__ float sigmoid_(float x) { return 1.0f / (1.0f + __expf(-x)); }
__device__ __forceinline__ float tanh_(float x)    { return 1.0f - 2.0f / (__expf(2.0f * x) + 1.0f); }

// Deterministic RNE fp32 -> bf16
__device__ __forceinline__ short f2bf(float f) {
  union { float f; unsigned u; } v; v.f = f;
  return (short)((v.u + 0x7FFFu + ((v.u >> 16) & 1u)) >> 16);
}

// --- per-access MALL-coherent ops (sc0 sc1 = bypass L1+L2, coherent point) ---
__device__ __forceinline__ void store_short_llc(void* p, unsigned v) {
  asm volatile("global_store_short %0, %1, off sc0 sc1" :: "v"(p), "v"(v) : "memory");
}
__device__ __forceinline__ void store_dword_llc(void* p, float v) {
  asm volatile("global_store_dword %0, %1, off sc0 sc1" :: "v"(p), "v"(v) : "memory");
}
// one coherent 16B load + drain (staging)
__device__ __forceinline__ f32x4 ld_b128_llc(const void* p) {
  f32x4 v;
  asm volatile("global_load_dwordx4 %0, %1, off sc0 sc1\n\ts_waitcnt vmcnt(0)"
               : "=&v"(v) : "v"(p) : "memory");
  return v;
}

// ---------------------------------------------------------------------------
// One-time W_ih fp32 -> bf16 converter (r9 win).
// ---------------------------------------------------------------------------
__global__ __launch_bounds__(256, 1) void wih_conv(const float* __restrict__ W,
                                                   short* __restrict__ out) {
  const int i = (blockIdx.x * 256 + threadIdx.x) * 4;   // grid 512 -> 524288 elems
  f32x4 v = *(const f32x4*)(W + i);
  s16x4 s;
  s[0] = f2bf(v[0]); s[1] = f2bf(v[1]); s[2] = f2bf(v[2]); s[3] = f2bf(v[3]);
  *(s16x4*)(out + i) = s;
}

// ---------------------------------------------------------------------------
// Phase 1: xg[t][g][b][d] — unchanged (r14 coalesced C-write version).
// ---------------------------------------------------------------------------
union XgSmem {
  struct { int idx[B_]; short e[B_][E_ + 8]; } g;   // gather phase (34 KB)
  short o[4][64][136];                              // epilogue staging (68 KB)
};

template<bool WBF16>
__global__ __launch_bounds__(256, 2) void xg_kernel(
    const int* __restrict__ x, const float* __restrict__ emb,
    const void* __restrict__ Wv,
    __hip_bfloat16* __restrict__ xg)
{
  const int t   = blockIdx.x;
  const int tid = threadIdx.x;
  __shared__ XgSmem sm;

  if (tid < B_) sm.g.idx[tid] = x[tid * T_ + t];
  __syncthreads();
  {
    int b = tid >> 2, ch = tid & 3;
    const float* src = emb + (size_t)sm.g.idx[b] * E_ + ch * 64;
    short* dst = &sm.g.e[b][ch * 64];
#pragma unroll
    for (int i = 0; i < 16; i++) {
      f32x4 v = *(const f32x4*)(src + i * 4);
      s16x4 s;
      s[0] = f2bf(v[0]); s[1] = f2bf(v[1]); s[2] = f2bf(v[2]); s[3] = f2bf(v[3]);
      *(s16x4*)(dst + i * 4) = s;
    }
  }
  __syncthreads();

  const int wv   = tid >> 6;
  const int lane = tid & 63;
  const int ln15 = lane & 15, quad = lane >> 4;

  V16 breg[4][8];
#pragma unroll
  for (int nt = 0; nt < 4; nt++)
#pragma unroll
    for (int ks = 0; ks < 8; ks++)
      breg[nt][ks].f = *(const f32x4*)(&sm.g.e[nt * 16 + ln15][quad * 8 + ks * 32]);
  __syncthreads();   // all waves done reading s_e before s_o overwrites it

  const int gbase = wv * 512;
  const size_t base_t = (size_t)t * (G4_ * B_);

  for (int q = 0; q < 4; q++) {
#pragma unroll
    for (int m8 = 0; m8 < 8; m8++) {
      const int mt = q * 8 + m8;
      V16 areg[8];
      if constexpr (WBF16) {
        const short* arow = (const short*)Wv + (size_t)(gbase + mt * 16 + ln15) * E_ + quad * 8;
#pragma unroll
        for (int ks = 0; ks < 8; ks++)
          areg[ks].f = *(const f32x4*)(arow + ks * 32);
      } else {
        const float* arow = (const float*)Wv + (size_t)(gbase + mt * 16 + ln15) * E_ + quad * 8;
#pragma unroll
        for (int ks = 0; ks < 8; ks++) {
          f32x4 lo = *(const f32x4*)(arow + ks * 32);
          f32x4 hi = *(const f32x4*)(arow + ks * 32 + 4);
          short8 s;
          s[0] = f2bf(lo[0]); s[1] = f2bf(lo[1]); s[2] = f2bf(lo[2]); s[3] = f2bf(lo[3]);
          s[4] = f2bf(hi[0]); s[5] = f2bf(hi[1]); s[6] = f2bf(hi[2]); s[7] = f2bf(hi[3]);
          areg[ks].s = s;
        }
      }

      f32x4 acc[4];
#pragma unroll
      for (int nt = 0; nt < 4; nt++) acc[nt] = (f32x4){0.f, 0.f, 0.f, 0.f};
#pragma unroll
      for (int ks = 0; ks < 8; ks++)
#pragma unroll
        for (int nt = 0; nt < 4; nt++)
          acc[nt] = __builtin_amdgcn_mfma_f32_16x16x32_bf16(areg[ks].b, breg[nt][ks].b, acc[nt], 0, 0, 0);

      const int dl = m8 * 16 + quad * 4;
#pragma unroll
      for (int nt = 0; nt < 4; nt++) {
        const int batch = nt * 16 + ln15;
        s16x4 sv;
#pragma unroll
        for (int r = 0; r < 4; r++) sv[r] = f2bf(acc[nt][r]);
        *(s16x4*)&sm.o[wv][batch][dl] = sv;
      }
    }

    const size_t qbase = base_t + ((size_t)wv << 15) + q * 128;
    const int chunk = lane & 15;
#pragma unroll
    for (int i = 0; i < 16; i++) {
      const int row = (lane >> 4) + i * 4;
      f32x4 v = *(const f32x4*)&sm.o[wv][row][chunk * 8];
      *(f32x4*)((short*)xg + qbase + ((size_t)row << 9) + chunk * 8) = v;
    }
  }
}

// ---------------------------------------------------------------------------
// Phase 2: persistent recurrent kernel — r10 PROTOCOL VERBATIM (flags +
// __hip_atomic poll + sc0sc1 MALL ops + S4 barrier-drain; proven 1118 us),
// with the ONE protocol-neutral improvement that is bitwise-verified (r15 run
// passed, absmax identical): GATE-REMAP. Wave wv owns all 4 gates of dims
// [d0+wv*8,+8); A-row m = gate(m&3), dim(m>>2); MFMA D layout (col=batch,
// row=quad*4+r, quad*4%4==0) puts gate r of dim (d0+wv*8+tau*4+quad) in
// acc[tau][r] -> gate math fully in registers; s_pre LDS + barrier S3 DELETED
// (4 -> 3 barriers/step). No rendezvous, no XCD cohorts, no vmcnt games
// (r16's novel parts — suspected hang source — all removed).
// ---------------------------------------------------------------------------
__global__ __launch_bounds__(512, 2) void lstm_kernel(
    const float* __restrict__ W_hh,
    const float* __restrict__ b_ih, const float* __restrict__ b_hh,
    const float* __restrict__ W_fc, const float* __restrict__ b_fc,
    const __hip_bfloat16* __restrict__ xg,
    unsigned int* flags, __hip_bfloat16* hbuf /*[2][64][512]*/, float* hT,
    float* out)
{
  const int tid  = threadIdx.x;
  const int blk  = blockIdx.x;
  const int g    = blk & 7;        // batch group (8 batches)
  const int pd   = blk >> 3;       // dim slice [pd*64, +64)
  const int d0   = pd * 64;
  const int wv   = tid >> 6;       // 0..7
  const int lane = tid & 63;
  const int ln15 = lane & 15, quad = lane >> 4;

  __shared__ __hip_bfloat16 s_h[16][520];   // rows 0-7: batches; 8-15: zeros

  // A-regs, gate-remapped (bitwise-verified mapping from the r15 run)
  V16 areg[2][16];
#pragma unroll
  for (int tau = 0; tau < 2; tau++) {
    const int grow = (ln15 & 3) * 512 + d0 + wv * 8 + tau * 4 + (ln15 >> 2);
    const float* ap = W_hh + (size_t)grow * H_ + quad * 8;
#pragma unroll
    for (int ks = 0; ks < 16; ks++) {
      f32x4 lo = *(const f32x4*)(ap + ks * 32);
      f32x4 hi = *(const f32x4*)(ap + ks * 32 + 4);
      short8 s;
      s[0] = f2bf(lo[0]); s[1] = f2bf(lo[1]); s[2] = f2bf(lo[2]); s[3] = f2bf(lo[3]);
      s[4] = f2bf(hi[0]); s[5] = f2bf(hi[1]); s[6] = f2bf(hi[2]); s[7] = f2bf(hi[3]);
      areg[tau][ks].s = s;
    }
  }

  // per-lane LSTM state (valid lanes: ln15 < 8)
  const int gb_ = g * 8 + ln15;               // global batch
  float bias[2][4];
  float cst[2] = {0.f, 0.f};
  if (ln15 < 8) {
#pragma unroll
    for (int tau = 0; tau < 2; tau++) {
      const int dg_ = d0 + wv * 8 + tau * 4 + quad;
#pragma unroll
      for (int gg = 0; gg < 4; gg++)
        bias[tau][gg] = b_ih[gg * 512 + dg_] + b_hh[gg * 512 + dg_];
    }
  }

  const int myflag = g * 16 + pd;

  // zero phantom batch rows 8-15 (MFMA B rows 8-15), published by S2 of t=0
  *(f32x4*)&s_h[8 + wv][lane * 8] = (f32x4){0.f, 0.f, 0.f, 0.f};

  for (int t = 0; t < T_; t++) {
    const int cur = t & 1, nxt = cur ^ 1;

    // xg loads at loop top (r10 placement: hidden under poll+staging+MFMA)
    __hip_bfloat16 xv[2][4];
    if (ln15 < 8) {
      const size_t xb = (size_t)t * (G4_ * B_) + ((size_t)gb_ << 9);
#pragma unroll
      for (int tau = 0; tau < 2; tau++) {
        const int dg_ = d0 + wv * 8 + tau * 4 + quad;
#pragma unroll
        for (int gg = 0; gg < 4; gg++)
          xv[tau][gg] = xg[xb + ((size_t)gg << 15) + dg_];
      }
    }

    if (tid < 8) {
      const unsigned* fp = flags + g * 16 + tid;
      while (__hip_atomic_load(fp, __ATOMIC_RELAXED, __HIP_MEMORY_SCOPE_AGENT) < (unsigned)t) {}
    }
    __syncthreads();   // S1: h_t visible at MALL

    {
      const short* hbase = (const short*)hbuf + (size_t)cur * (B_ * H_) + (size_t)(g * 8) * H_;
      f32x4 va = ld_b128_llc(hbase + tid * 8);
      *(f32x4*)&s_h[tid >> 6][(tid & 63) * 8] = va;
    }
    __syncthreads();   // S2: LDS staging complete

    f32x4 acc0 = (f32x4){0.f, 0.f, 0.f, 0.f};
    f32x4 acc1 = (f32x4){0.f, 0.f, 0.f, 0.f};
#pragma unroll
    for (int ks = 0; ks < 16; ks++) {
      V16 b0;
      b0.f = *(const f32x4*)&s_h[ln15][quad * 8 + ks * 32];
      acc0 = __builtin_amdgcn_mfma_f32_16x16x32_bf16(areg[0][ks].b, b0.b, acc0, 0, 0, 0);
      acc1 = __builtin_amdgcn_mfma_f32_16x16x32_bf16(areg[1][ks].b, b0.b, acc1, 0, 0, 0);
    }

    if (ln15 < 8) {
      short* sb = (short*)hbuf + (size_t)nxt * (B_ * H_) + (size_t)gb_ * H_;
#pragma unroll
      for (int tau = 0; tau < 2; tau++) {
        const f32x4 a = tau ? acc1 : acc0;
        const float pi = a[0] + bias[tau][0] + __bfloat162float(xv[tau][0]);
        const float pf = a[1] + bias[tau][1] + __bfloat162float(xv[tau][1]);
        const float pg = a[2] + bias[tau][2] + __bfloat162float(xv[tau][2]);
        const float po = a[3] + bias[tau][3] + __bfloat162float(xv[tau][3]);
        const float i_ = sigmoid_(pi), f_ = sigmoid_(pf);
        const float g_ = tanh_(pg),    o_ = sigmoid_(po);
        cst[tau] = f_ * cst[tau] + i_ * g_;
        const float h = o_ * tanh_(cst[tau]);
        const int dg_ = d0 + wv * 8 + tau * 4 + quad;
        if (t < T_ - 1)
          store_short_llc(sb + dg_, (unsigned)(unsigned short)f2bf(h));
        else
          store_dword_llc(hT + gb_ * H_ + dg_, h);
      }
    }
    __syncthreads();   // S4: implicit vmcnt(0) drain -> h stores acked at MALL

    if (tid == 0)
      __hip_atomic_store(&flags[myflag], (unsigned)(t + 1),
                         __ATOMIC_RELAXED, __HIP_MEMORY_SCOPE_AGENT);
  }

  // Phase 3: fp32 FC by block 0 (r10 verbatim)
  if (blk == 0) {
    if (tid < 64)
      while (__hip_atomic_load(flags + (tid >> 3) * 16 + (tid & 7),
                               __ATOMIC_RELAXED, __HIP_MEMORY_SCOPE_AGENT) < (unsigned)T_) {}
    __builtin_amdgcn_fence(__ATOMIC_ACQUIRE, "agent");
    __syncthreads();
    for (int o = tid; o < B_ * C_; o += 512) {
      const int b = o >> 2, cl = o & 3;
      const f32x4* hr = (const f32x4*)(hT + b * H_);
      const f32x4* wr = (const f32x4*)(W_fc + cl * H_);
      float s = 0.f;
      for (int d4 = 0; d4 < H_ / 4; d4++) {
        const f32x4 hv = hr[d4];
        const f32x4 wv4 = wr[d4];
        s += hv[0] * wv4[0] + hv[1] * wv4[1] + hv[2] * wv4[2] + hv[3] * wv4[3];
      }
      s += b_fc[cl];
      out[o] = s;
    }
  }
}

// ---------------------------------------------------------------------------
// Workspace map (r10 layout):
//   [0, 1024)            : flags[256] (group g's 8 flags at words [g*16,+8))
//   [4096, 135168)       : hbuf[2][64][512] bf16 (zeroed = h0)
//   [135168, 266240)     : hT[64][512] fp32
//   [524288, 134742016)  : xg[T][4][B][512] bf16 (128 MiB)
//   [134742016, 135790592): W_ih bf16 table (1 MiB) — only if ws_size allows
// ---------------------------------------------------------------------------
extern "C" void kernel_launch(void* const* d_in, const int* in_sizes, int n_in,
                              void* d_out, int out_size, void* d_ws, size_t ws_size,
                              hipStream_t stream) {
  const int*   x    = (const int*)d_in[0];
  const float* emb  = (const float*)d_in[1];
  const float* W_ih = (const float*)d_in[2];
  const float* W_hh = (const float*)d_in[3];
  const float* b_ih = (const float*)d_in[4];
  const float* b_hh = (const float*)d_in[5];
  const float* W_fc = (const float*)d_in[6];
  const float* b_fc = (const float*)d_in[7];
  float* out = (float*)d_out;

  char* ws = (char*)d_ws;
  const size_t XG_OFF  = 524288;
  const size_t XG_END  = XG_OFF + (size_t)T_ * G4_ * B_ * 2;   // 134,742,016
  const size_t NEEDED2 = XG_END + (size_t)G4_ * E_ * 2;        // +1 MiB bf16 W_ih
  if (ws_size < XG_END) return;

  unsigned int*   flags = (unsigned int*)ws;
  __hip_bfloat16* hbuf  = (__hip_bfloat16*)(ws + 4096);
  float*          hT    = (float*)(ws + 135168);
  __hip_bfloat16* xg    = (__hip_bfloat16*)(ws + XG_OFF);
  short*          wih16 = (short*)(ws + XG_END);

  (void)hipMemsetAsync(ws, 0, 135168, stream);

  if (ws_size >= NEEDED2) {
    wih_conv<<<512, 256, 0, stream>>>(W_ih, wih16);
    xg_kernel<true><<<T_, 256, 0, stream>>>(x, emb, wih16, xg);
  } else {
    xg_kernel<false><<<T_, 256, 0, stream>>>(x, emb, W_ih, xg);
  }
  lstm_kernel<<<64, 512, 0, stream>>>(W_hh, b_ih, b_hh, W_fc, b_fc, xg,
                                      flags, hbuf, hT, out);
}

// Round 6
// 1277.082 us; speedup vs baseline: 1.7486x; 1.2974x over previous
//
#include <hip/hip_runtime.h>
#include <hip/hip_bf16.h>

// Problem constants
#define B_  64
#define T_  512
#define E_  256
#define H_  512
#define G4_ 2048
#define C_  4

typedef __attribute__((ext_vector_type(4))) float  f32x4;
typedef __attribute__((ext_vector_type(8))) __bf16 bf16x8;
typedef __attribute__((ext_vector_type(8))) short  short8;   // no HIP builtin 'short8'
typedef __attribute__((ext_vector_type(4))) short  s16x4;    // HIP predefines 'short4'

union V16 { f32x4 f; bf16x8 b; short8 s; };

__device__ __forceinline__ float sigmoid_(float x) { return 1.0f / (1.0f + __expf(-x)); }
__device__ __forceinline__ float tanh_(float x)    { return 1.0f - 2.0f / (__expf(2.0f * x) + 1.0f); }

// Deterministic RNE fp32 -> bf16
__device__ __forceinline__ short f2bf(float f) {
  union { float f; unsigned u; } v; v.f = f;
  return (short)((v.u + 0x7FFFu + ((v.u >> 16) & 1u)) >> 16);
}

// --- per-access MALL-coherent ops (sc0 sc1 = bypass L1+L2, coherent point) ---
__device__ __forceinline__ void store_dword_llc_f(void* p, float v) {
  asm volatile("global_store_dword %0, %1, off sc0 sc1" :: "v"(p), "v"(v) : "memory");
}
__device__ __forceinline__ void store_dword_llc_u(void* p, unsigned v) {
  asm volatile("global_store_dword %0, %1, off sc0 sc1" :: "v"(p), "v"(v) : "memory");
}
// two coherent 16B loads, one drain (poll quantum = 32 B).
// gfx950 assembler: offset: must precede sc0 sc1. (compiled+ran in r15)
__device__ __forceinline__ void ld2_b128_llc(const void* p, f32x4& a, f32x4& b) {
  asm volatile("global_load_dwordx4 %0, %2, off sc0 sc1\n\t"
               "global_load_dwordx4 %1, %2, off offset:16 sc0 sc1\n\t"
               "s_waitcnt vmcnt(0)"
               : "=&v"(a), "=&v"(b) : "v"(p) : "memory");
}

// ---------------------------------------------------------------------------
// One-time W_ih fp32 -> bf16 converter (r9 win).
// ---------------------------------------------------------------------------
__global__ __launch_bounds__(256, 1) void wih_conv(const float* __restrict__ W,
                                                   short* __restrict__ out) {
  const int i = (blockIdx.x * 256 + threadIdx.x) * 4;   // grid 512 -> 524288 elems
  f32x4 v = *(const f32x4*)(W + i);
  s16x4 s;
  s[0] = f2bf(v[0]); s[1] = f2bf(v[1]); s[2] = f2bf(v[2]); s[3] = f2bf(v[3]);
  *(s16x4*)(out + i) = s;
}

// ---------------------------------------------------------------------------
// Phase 1: xg[t][g][b][d] — r14 coalesced C-write version, SEPARATE dispatch
// (proven 145us; cross-kernel visibility via end-of-kernel cache flush).
// ---------------------------------------------------------------------------
union XgSmem {
  struct { int idx[B_]; short e[B_][E_ + 8]; } g;   // gather phase (34 KB)
  short o[4][64][136];                              // epilogue staging (68 KB)
};

template<bool WBF16>
__global__ __launch_bounds__(256, 2) void xg_kernel(
    const int* __restrict__ x, const float* __restrict__ emb,
    const void* __restrict__ Wv,
    __hip_bfloat16* __restrict__ xg)
{
  const int t   = blockIdx.x;
  const int tid = threadIdx.x;
  __shared__ XgSmem sm;

  if (tid < B_) sm.g.idx[tid] = x[tid * T_ + t];
  __syncthreads();
  {
    int b = tid >> 2, ch = tid & 3;
    const float* src = emb + (size_t)sm.g.idx[b] * E_ + ch * 64;
    short* dst = &sm.g.e[b][ch * 64];
#pragma unroll
    for (int i = 0; i < 16; i++) {
      f32x4 v = *(const f32x4*)(src + i * 4);
      s16x4 s;
      s[0] = f2bf(v[0]); s[1] = f2bf(v[1]); s[2] = f2bf(v[2]); s[3] = f2bf(v[3]);
      *(s16x4*)(dst + i * 4) = s;
    }
  }
  __syncthreads();

  const int wv   = tid >> 6;
  const int lane = tid & 63;
  const int ln15 = lane & 15, quad = lane >> 4;

  V16 breg[4][8];
#pragma unroll
  for (int nt = 0; nt < 4; nt++)
#pragma unroll
    for (int ks = 0; ks < 8; ks++)
      breg[nt][ks].f = *(const f32x4*)(&sm.g.e[nt * 16 + ln15][quad * 8 + ks * 32]);
  __syncthreads();   // all waves done reading s_e before s_o overwrites it

  const int gbase = wv * 512;
  const size_t base_t = (size_t)t * (G4_ * B_);

  for (int q = 0; q < 4; q++) {
#pragma unroll
    for (int m8 = 0; m8 < 8; m8++) {
      const int mt = q * 8 + m8;
      V16 areg[8];
      if constexpr (WBF16) {
        const short* arow = (const short*)Wv + (size_t)(gbase + mt * 16 + ln15) * E_ + quad * 8;
#pragma unroll
        for (int ks = 0; ks < 8; ks++)
          areg[ks].f = *(const f32x4*)(arow + ks * 32);
      } else {
        const float* arow = (const float*)Wv + (size_t)(gbase + mt * 16 + ln15) * E_ + quad * 8;
#pragma unroll
        for (int ks = 0; ks < 8; ks++) {
          f32x4 lo = *(const f32x4*)(arow + ks * 32);
          f32x4 hi = *(const f32x4*)(arow + ks * 32 + 4);
          short8 s;
          s[0] = f2bf(lo[0]); s[1] = f2bf(lo[1]); s[2] = f2bf(lo[2]); s[3] = f2bf(lo[3]);
          s[4] = f2bf(hi[0]); s[5] = f2bf(hi[1]); s[6] = f2bf(hi[2]); s[7] = f2bf(hi[3]);
          areg[ks].s = s;
        }
      }

      f32x4 acc[4];
#pragma unroll
      for (int nt = 0; nt < 4; nt++) acc[nt] = (f32x4){0.f, 0.f, 0.f, 0.f};
#pragma unroll
      for (int ks = 0; ks < 8; ks++)
#pragma unroll
        for (int nt = 0; nt < 4; nt++)
          acc[nt] = __builtin_amdgcn_mfma_f32_16x16x32_bf16(areg[ks].b, breg[nt][ks].b, acc[nt], 0, 0, 0);

      const int dl = m8 * 16 + quad * 4;
#pragma unroll
      for (int nt = 0; nt < 4; nt++) {
        const int batch = nt * 16 + ln15;
        s16x4 sv;
#pragma unroll
        for (int r = 0; r < 4; r++) sv[r] = f2bf(acc[nt][r]);
        *(s16x4*)&sm.o[wv][batch][dl] = sv;
      }
    }

    const size_t qbase = base_t + ((size_t)wv << 15) + q * 128;
    const int chunk = lane & 15;
#pragma unroll
    for (int i = 0; i < 16; i++) {
      const int row = (lane >> 4) + i * 4;
      f32x4 v = *(const f32x4*)&sm.o[wv][row][chunk * 8];
      *(f32x4*)((short*)xg + qbase + ((size_t)row << 9) + chunk * 8) = v;
    }
  }
}

// ---------------------------------------------------------------------------
// Phase 2: r10 SKELETON + EPOCH-FUSED h exchange (r19).
// Exchange dword = (epoch<<16)|bf16(h). Producer side uses r10's EXACT
// coalesced thread mapping: thread (nb=tid>>6, nd=tid&63) stores ONE dword at
// [slot][gb][dg] -> wave = 256B contiguous (r15/r17 proved scatter costs
// ~4x write amplification; this layout avoids it). Consumer thread polls its
// own 32B (8 dwords, 2KB/wave contiguous) until all epochs == t -- the poll
// IS the staging load (replaces S1 flag-poll + ld_b128 staging). No flags,
// no S4 drain: 4 barriers -> 2, ~3 MALL RTs -> ~1 per step.
// Depth-2 slot reuse safety = r15's HW-verified argument: a block writes
// slot A with epoch t+1 only after its poll of epoch t, which proves every
// peer block finished reading A at t-1.
// Gate staging via s_pre + S3 kept (r10 verbatim; r17 taught us not to
// scatter stores to save a barrier).
// ---------------------------------------------------------------------------
__global__ __launch_bounds__(512, 2) void lstm_kernel(
    const float* __restrict__ W_hh,
    const float* __restrict__ b_ih, const float* __restrict__ b_hh,
    const float* __restrict__ W_fc, const float* __restrict__ b_fc,
    const __hip_bfloat16* __restrict__ xg,
    unsigned int* flags2, unsigned int* hbuf /*[2][64][512] dwords*/, float* hT,
    float* out)
{
  const int tid  = threadIdx.x;
  const int blk  = blockIdx.x;
  const int g    = blk & 7;        // batch group (8 batches)
  const int pd   = blk >> 3;       // dim slice [pd*64, +64)
  const int d0   = pd * 64;
  const int wv   = tid >> 6;       // 0..7
  const int lane = tid & 63;
  const int ln15 = lane & 15, quad = lane >> 4;

  __shared__ __hip_bfloat16 s_h[16][520];   // rows 0-7: batches; 8-15: zeros
  __shared__ float s_pre[4][8][68];         // [gate][batch][dim(+4 pad)]

  const int gate  = wv >> 1;
  const int dhalf = (wv & 1) * 32;
  V16 areg[2][16];
#pragma unroll
  for (int tau = 0; tau < 2; tau++) {
    const int grow = gate * 512 + d0 + dhalf + tau * 16 + ln15;
    const float* ap = W_hh + (size_t)grow * H_ + quad * 8;
#pragma unroll
    for (int ks = 0; ks < 16; ks++) {
      f32x4 lo = *(const f32x4*)(ap + ks * 32);
      f32x4 hi = *(const f32x4*)(ap + ks * 32 + 4);
      short8 s;
      s[0] = f2bf(lo[0]); s[1] = f2bf(lo[1]); s[2] = f2bf(lo[2]); s[3] = f2bf(lo[3]);
      s[4] = f2bf(hi[0]); s[5] = f2bf(hi[1]); s[6] = f2bf(hi[2]); s[7] = f2bf(hi[3]);
      areg[tau][ks].s = s;
    }
  }

  const int nb = tid >> 6;         // 0..7  (== wv)
  const int nd = tid & 63;         // 0..63
  const int gb = g * 8 + nb;       // global batch
  const int dg = d0 + nd;          // global h-dim
  const float bias_i = b_ih[dg]        + b_hh[dg];
  const float bias_f = b_ih[512 + dg]  + b_hh[512 + dg];
  const float bias_g = b_ih[1024 + dg] + b_hh[1024 + dg];
  const float bias_o = b_ih[1536 + dg] + b_hh[1536 + dg];
  float c = 0.0f;

  // zero phantom batch rows 8-15 (MFMA B rows 8-15), published by S2 of t=0
  *(f32x4*)&s_h[8 + wv][lane * 8] = (f32x4){0.f, 0.f, 0.f, 0.f};

  // poll/stage base: thread covers batch g*8+(tid>>6), dims (tid&63)*8..+8
  // (tid*8 == (tid>>6)*512 + (tid&63)*8)
  const unsigned* hb0 = hbuf + ((size_t)(g * 8) << 9) + tid * 8;
  const unsigned* hb1 = hb0 + B_ * H_;

  for (int t = 0; t < T_; t++) {
    const int nxt = (t & 1) ^ 1;

    // xg loads at loop top (r10 placement: hidden under poll+MFMA)
    const size_t xoff = (size_t)t * (G4_ * B_) + ((size_t)gb << 9) + dg;
    const __hip_bfloat16 xgi = xg[xoff];
    const __hip_bfloat16 xgf = xg[xoff + (1u << 15)];
    const __hip_bfloat16 xgg = xg[xoff + (2u << 15)];
    const __hip_bfloat16 xgo = xg[xoff + (3u << 15)];

    // ---- poll h(t): every dword self-validates via its epoch (high 16) ----
    {
      const unsigned want = (unsigned)t;
      const unsigned* hb = (t & 1) ? hb1 : hb0;
      f32x4 va, vb;
      for (;;) {
        ld2_b128_llc(hb, va, vb);
        unsigned bad = 0;
#pragma unroll
        for (int i = 0; i < 4; i++) {
          bad |= (__float_as_uint(va[i]) >> 16) ^ want;
          bad |= (__float_as_uint(vb[i]) >> 16) ^ want;
        }
        if (!bad) break;
      }
      short8 sv;
      sv[0] = (short)(__float_as_uint(va[0]) & 0xffffu);
      sv[1] = (short)(__float_as_uint(va[1]) & 0xffffu);
      sv[2] = (short)(__float_as_uint(va[2]) & 0xffffu);
      sv[3] = (short)(__float_as_uint(va[3]) & 0xffffu);
      sv[4] = (short)(__float_as_uint(vb[0]) & 0xffffu);
      sv[5] = (short)(__float_as_uint(vb[1]) & 0xffffu);
      sv[6] = (short)(__float_as_uint(vb[2]) & 0xffffu);
      sv[7] = (short)(__float_as_uint(vb[3]) & 0xffffu);
      *(short8*)&s_h[tid >> 6][(tid & 63) * 8] = sv;
    }
    __syncthreads();   // S2: all waves staged h(t) into LDS

    f32x4 acc0 = (f32x4){0.f, 0.f, 0.f, 0.f};
    f32x4 acc1 = (f32x4){0.f, 0.f, 0.f, 0.f};
#pragma unroll
    for (int ks = 0; ks < 16; ks++) {
      V16 b0;
      b0.f = *(const f32x4*)&s_h[ln15][quad * 8 + ks * 32];
      acc0 = __builtin_amdgcn_mfma_f32_16x16x32_bf16(areg[0][ks].b, b0.b, acc0, 0, 0, 0);
      acc1 = __builtin_amdgcn_mfma_f32_16x16x32_bf16(areg[1][ks].b, b0.b, acc1, 0, 0, 0);
    }

    if (ln15 < 8) {
      *(f32x4*)&s_pre[gate][ln15][dhalf + quad * 4]      = acc0;
      *(f32x4*)&s_pre[gate][ln15][dhalf + 16 + quad * 4] = acc1;
    }
    __syncthreads();   // S3: preactivations complete

    {
      const float pi = s_pre[0][nb][nd] + bias_i + __bfloat162float(xgi);
      const float pf = s_pre[1][nb][nd] + bias_f + __bfloat162float(xgf);
      const float pg = s_pre[2][nb][nd] + bias_g + __bfloat162float(xgg);
      const float po = s_pre[3][nb][nd] + bias_o + __bfloat162float(xgo);
      const float i_ = sigmoid_(pi), f_ = sigmoid_(pf);
      const float g_ = tanh_(pg),    o_ = sigmoid_(po);
      c = f_ * c + i_ * g_;
      const float h = o_ * tanh_(c);
      if (t < T_ - 1) {
        // fire-and-forget epoch-packed dword; wave = 256B contiguous
        const unsigned pw = ((unsigned)(t + 1) << 16) | (unsigned)(unsigned short)f2bf(h);
        store_dword_llc_u(hbuf + (size_t)nxt * (B_ * H_) + ((size_t)gb << 9) + dg, pw);
      } else {
        store_dword_llc_f(hT + gb * H_ + dg, h);
      }
    }
    // no S4, no flag: the data IS the flag
  }

  // one-time completion handoff for the FC epilogue
  asm volatile("s_waitcnt vmcnt(0)" ::: "memory");
  __syncthreads();
  if (tid == 0)
    __hip_atomic_store(&flags2[blk], 1u,
                       __ATOMIC_RELEASE, __HIP_MEMORY_SCOPE_AGENT);

  // Phase 3: fp32 FC by block 0
  if (blk == 0) {
    if (tid < 64)
      while (__hip_atomic_load(&flags2[tid],
                               __ATOMIC_RELAXED, __HIP_MEMORY_SCOPE_AGENT) < 1u) {}
    __builtin_amdgcn_fence(__ATOMIC_ACQUIRE, "agent");
    __syncthreads();
    for (int o = tid; o < B_ * C_; o += 512) {
      const int b = o >> 2, cl = o & 3;
      const f32x4* hr = (const f32x4*)(hT + b * H_);
      const f32x4* wr = (const f32x4*)(W_fc + cl * H_);
      float s = 0.f;
      for (int d4 = 0; d4 < H_ / 4; d4++) {
        const f32x4 hv = hr[d4];
        const f32x4 wv4 = wr[d4];
        s += hv[0] * wv4[0] + hv[1] * wv4[1] + hv[2] * wv4[2] + hv[3] * wv4[3];
      }
      s += b_fc[cl];
      out[o] = s;
    }
  }
}

// ---------------------------------------------------------------------------
// Workspace map:
//   [0, 1024)            : ctl; flags2[64] at words [256,320) (completion)
//   [4096, 266240)       : hbuf[2][64][512] dwords: (epoch<<16)|bf16(h)
//                          (memset 0 == epoch 0 + h0 == 0: t=0 passes free)
//   [266240, 397312)     : hT[64][512] fp32
//   [524288, 134742016)  : xg[T][4][B][512] bf16 (128 MiB)
//   [134742016, 135790592): W_ih bf16 table (1 MiB) — only if ws_size allows
// ---------------------------------------------------------------------------
extern "C" void kernel_launch(void* const* d_in, const int* in_sizes, int n_in,
                              void* d_out, int out_size, void* d_ws, size_t ws_size,
                              hipStream_t stream) {
  const int*   x    = (const int*)d_in[0];
  const float* emb  = (const float*)d_in[1];
  const float* W_ih = (const float*)d_in[2];
  const float* W_hh = (const float*)d_in[3];
  const float* b_ih = (const float*)d_in[4];
  const float* b_hh = (const float*)d_in[5];
  const float* W_fc = (const float*)d_in[6];
  const float* b_fc = (const float*)d_in[7];
  float* out = (float*)d_out;

  char* ws = (char*)d_ws;
  const size_t XG_OFF  = 524288;
  const size_t XG_END  = XG_OFF + (size_t)T_ * G4_ * B_ * 2;   // 134,742,016
  const size_t NEEDED2 = XG_END + (size_t)G4_ * E_ * 2;        // +1 MiB bf16 W_ih
  if (ws_size < XG_END) return;

  unsigned int*   ctl    = (unsigned int*)ws;
  unsigned int*   flags2 = ctl + 256;
  unsigned int*   hbuf   = (unsigned int*)(ws + 4096);
  float*          hT     = (float*)(ws + 266240);
  __hip_bfloat16* xg     = (__hip_bfloat16*)(ws + XG_OFF);
  short*          wih16  = (short*)(ws + XG_END);

  (void)hipMemsetAsync(ws, 0, 266240, stream);

  if (ws_size >= NEEDED2) {
    wih_conv<<<512, 256, 0, stream>>>(W_ih, wih16);
    xg_kernel<true><<<T_, 256, 0, stream>>>(x, emb, wih16, xg);
  } else {
    xg_kernel<false><<<T_, 256, 0, stream>>>(x, emb, W_ih, xg);
  }
  lstm_kernel<<<64, 512, 0, stream>>>(W_hh, b_ih, b_hh, W_fc, b_fc, xg,
                                      flags2, hbuf, hT, out);
}